// Round 3
// baseline (252.921 us; speedup 1.0000x reference)
//
#include <hip/hip_runtime.h>
#include <hip/hip_bf16.h>

// ALiBi causal attention, B=2 T=2048 C=1024 H=16 D=64.
// Round 3: dual-dtype (fp32 OR bf16 inputs, runtime-detected device-side).
// Theory: harness delivers fp32 (per reference dtypes); prior NaNs came from
// reading fp32 bits as bf16 (mantissa halves -> NaN/1e38 patterns -> MFMA).
// Intermediates f16 in ws (32 MB). Matmul via v_mfma_f32_16x16x16_f16, fp32 acc.

typedef _Float16 f16;
typedef f16 f16x4 __attribute__((ext_vector_type(4)));
typedef f16 f16x8 __attribute__((ext_vector_type(8)));
typedef float f32x4 __attribute__((ext_vector_type(4)));
typedef unsigned short u16;
typedef u16 u16x8 __attribute__((ext_vector_type(8)));

#define LOG2E 1.4426950408889634f
#define LDK 40   // GEMM LDS row stride in halves: 80B rows -> b128 stores aligned
#define LDKK 72  // attn K-tile row stride (64+8): 144B rows
#define LDVT 68  // attn V^T-tile row stride (64+4): 136B rows

__device__ __forceinline__ float bf2f(u16 b) {
  return __builtin_bit_cast(float, ((unsigned)b) << 16);
}
__device__ __forceinline__ u16 f2bf(float f) {  // RNE
  unsigned u = __builtin_bit_cast(unsigned, f);
  unsigned r = u + 0x7FFFu + ((u >> 16) & 1u);
  return (u16)(r >> 16);
}

// Detect whether buffer w (a weight tensor ~N(0,0.02^2)) is bf16 or fp32.
// bf16: every even-index u16 word is a real value -> exponent in [96,125].
// fp32: even words are low mantissa halves -> exponent uniform; P(pass)~1e-8.
__device__ __forceinline__ bool detect_bf16(const u16* w) {
  bool ok = true;
#pragma unroll
  for (int i = 0; i < 16; i += 2) {
    int e = (w[i] >> 7) & 0xFF;
    ok = ok && (e >= 96 && e <= 125);
  }
  return ok;
}

// MODE: 0 = native f16, 1 = bf16, 2 = fp32. Load 8 consecutive elements.
template <int M>
__device__ __forceinline__ f16x8 load8(const void* p, int idx) {
  f16x8 o;
  if (M == 0) {
    o = *(const f16x8*)((const f16*)p + idx);
  } else if (M == 1) {
    u16x8 v = *(const u16x8*)((const u16*)p + idx);
#pragma unroll
    for (int j = 0; j < 8; j++) o[j] = (f16)bf2f(v[j]);
  } else {
    const float* f = (const float*)p + idx;
    f32x4 a = *(const f32x4*)f;
    f32x4 b = *(const f32x4*)(f + 4);
#pragma unroll
    for (int j = 0; j < 4; j++) { o[j] = (f16)a[j]; o[j + 4] = (f16)b[j]; }
  }
  return o;
}

// ------------------------------------------------------- shared GEMM mainloop
// C[m][n] = sum_k A[m][k]*W[n][k]; A,W row-major, K=1024 contiguous.
// 128x128 tile, BK=32, 4 waves 2x2, each wave 64x64 = 4x4 MFMA tiles.
template <int AM, int WM>
__device__ __forceinline__ void gemm_core(const void* __restrict__ A,
                                          const void* __restrict__ W,
                                          int m0, int n0,
                                          f16* lA, f16* lW,
                                          f32x4 acc[4][4]) {
  const int tid = threadIdx.x;
  const int lane = tid & 63;
  const int w = tid >> 6;
  const int wm = w & 1, wn = w >> 1;
  const int q = lane & 15, quad = lane >> 4;
  const int seg = tid & 3;    // 8-elem segment of the 32-wide k slice
  const int row0 = tid >> 2;  // 0..63

  for (int kt = 0; kt < 1024; kt += 32) {
    __syncthreads();
#pragma unroll
    for (int it = 0; it < 2; it++) {
      int r = row0 + it * 64;
      *(f16x8*)(lA + r * LDK + seg * 8) =
          load8<AM>(A, (m0 + r) * 1024 + kt + seg * 8);
      *(f16x8*)(lW + r * LDK + seg * 8) =
          load8<WM>(W, (n0 + r) * 1024 + kt + seg * 8);
    }
    __syncthreads();
#pragma unroll
    for (int ks = 0; ks < 2; ks++) {
      f16x4 aF[4], bF[4];
#pragma unroll
      for (int mt = 0; mt < 4; mt++)
        aF[mt] = *(const f16x4*)(lA + (wm * 64 + mt * 16 + q) * LDK + ks * 16 + quad * 4);
#pragma unroll
      for (int nt = 0; nt < 4; nt++)
        bF[nt] = *(const f16x4*)(lW + (wn * 64 + nt * 16 + q) * LDK + ks * 16 + quad * 4);
#pragma unroll
      for (int mt = 0; mt < 4; mt++)
#pragma unroll
        for (int nt = 0; nt < 4; nt++)
          acc[mt][nt] = __builtin_amdgcn_mfma_f32_16x16x16f16(aF[mt], bF[nt], acc[mt][nt], 0, 0, 0);
    }
  }
}

// ------------------------------------------------------------ QKV projection
// grid (32,8,3): z picks Wq/Wk/Wv; epilogue scatters f16 to (B,H,T,D).
// Q pre-scaled by D^-0.5 * log2(e) so softmax runs in exp2 domain.
__global__ __launch_bounds__(256) void qkv_proj(
    const void* __restrict__ x, const void* __restrict__ wq,
    const void* __restrict__ wk, const void* __restrict__ wv,
    f16* __restrict__ qb, f16* __restrict__ kb, f16* __restrict__ vb,
    float qscale) {
  __shared__ __align__(16) f16 lA[128 * LDK];
  __shared__ __align__(16) f16 lW[128 * LDK];
  const int m0 = blockIdx.x * 128, n0 = blockIdx.y * 128;
  const int z = blockIdx.z;
  const void* W = (z == 0) ? wq : (z == 1) ? wk : wv;
  f16* out = (z == 0) ? qb : (z == 1) ? kb : vb;
  const float scale = (z == 0) ? qscale : 1.0f;

  f32x4 acc[4][4];
  const f32x4 zero = {0.f, 0.f, 0.f, 0.f};
#pragma unroll
  for (int i = 0; i < 4; i++)
#pragma unroll
    for (int j = 0; j < 4; j++) acc[i][j] = zero;

  if (detect_bf16((const u16*)wq))
    gemm_core<1, 1>(x, W, m0, n0, lA, lW, acc);
  else
    gemm_core<2, 2>(x, W, m0, n0, lA, lW, acc);

  const int tid = threadIdx.x, lane = tid & 63, w = tid >> 6;
  const int wm = w & 1, wn = w >> 1, q = lane & 15, quad = lane >> 4;
#pragma unroll
  for (int mt = 0; mt < 4; mt++)
#pragma unroll
    for (int nt = 0; nt < 4; nt++) {
      int n = n0 + wn * 64 + nt * 16 + q;
      int h = n >> 6, d = n & 63;
#pragma unroll
      for (int r = 0; r < 4; r++) {
        int mm = m0 + wm * 64 + mt * 16 + quad * 4 + r;
        int bb = mm >> 11, tl = mm & 2047;
        out[((bb * 16 + h) * 2048 + tl) * 64 + d] = (f16)(acc[mt][nt][r] * scale);
      }
    }
}

// --------------------------------------------------------------- attention
// grid (32, 32): x = q-block of 64 rows, y = (b,h). 4 waves; wave w owns 16 Q rows.
// Per 64-kv stage: S^T = K·Q^T (MFMA), ALiBi+mask, online softmax, O^T += V^T·P^T.
// P^T's C/D register layout IS the B-operand layout of 16x16x16 MFMA -> direct reuse.
__global__ __launch_bounds__(256) void attn(
    const f16* __restrict__ qB, const f16* __restrict__ kB,
    const f16* __restrict__ vB, f16* __restrict__ att) {
  __shared__ __align__(16) f16 lK[64 * LDKK];  // [kv][d]
  __shared__ __align__(16) f16 lV[64 * LDVT];  // [d][kv]
  const int tid = threadIdx.x, lane = tid & 63, w = tid >> 6;
  const int q = lane & 15, quad = lane >> 4;
  const int qb_ = blockIdx.x, bh = blockIdx.y;
  const int b = bh >> 4, h = bh & 15;
  const int q0 = qb_ * 64;
  const f16* qP = qB + (bh * 2048) * 64;
  const f16* kP = kB + (bh * 2048) * 64;
  const f16* vP = vB + (bh * 2048) * 64;

  // H=16 => slope_h = 2^(-(h+1)/2); fold log2(e) for exp2-domain softmax
  const float slope2 = __builtin_amdgcn_exp2f(-0.5f * (float)(h + 1)) * LOG2E;

  const int qg = q0 + w * 16 + q;
  f16x4 qF[4];
#pragma unroll
  for (int ks = 0; ks < 4; ks++)
    qF[ks] = *(const f16x4*)(qP + qg * 64 + ks * 16 + quad * 4);

  const f32x4 zero = {0.f, 0.f, 0.f, 0.f};
  f32x4 ot[4];
#pragma unroll
  for (int i = 0; i < 4; i++) ot[i] = zero;
  float m_i = -3e38f, l_i = 0.0f;

  const int nst = qb_ + 1;  // causal: kv tiles 0..qb_
  for (int s = 0; s < nst; s++) {
    const int kv0 = s * 64;
    __syncthreads();
#pragma unroll
    for (int it = 0; it < 2; it++) {  // stage K [kv][d]
      int c = it * 256 + tid;
      int row = c >> 3, sg = c & 7;
      *(f16x8*)(lK + row * LDKK + sg * 8) =
          *(const f16x8*)(kP + (kv0 + row) * 64 + sg * 8);
    }
#pragma unroll
    for (int it = 0; it < 2; it++) {  // stage V transposed -> [d][kv]
      int sg = it * 4 + w;
      f16x8 v8 = *(const f16x8*)(vP + (kv0 + lane) * 64 + sg * 8);
#pragma unroll
      for (int i2 = 0; i2 < 8; i2++) lV[(sg * 8 + i2) * LDVT + lane] = v8[i2];
    }
    __syncthreads();

    // S^T: St[kv = sub*16 + quad*4 + r][q = lane&15]
    f32x4 st[4];
#pragma unroll
    for (int sub = 0; sub < 4; sub++) {
      f32x4 a = zero;
#pragma unroll
      for (int ks = 0; ks < 4; ks++) {
        f16x4 kF = *(const f16x4*)(lK + (sub * 16 + q) * LDKK + ks * 16 + quad * 4);
        a = __builtin_amdgcn_mfma_f32_16x16x16f16(kF, qF[ks], a, 0, 0, 0);
      }
      st[sub] = a;
    }
    // ALiBi bias + causal mask + row max (rows spread across quads)
    float vmax = -3e38f;
#pragma unroll
    for (int sub = 0; sub < 4; sub++)
#pragma unroll
      for (int r = 0; r < 4; r++) {
        int kvg = kv0 + sub * 16 + quad * 4 + r;
        float dd = (float)(qg - kvg);
        float val = (dd >= 0.0f) ? (st[sub][r] - slope2 * dd) : -3e38f;
        st[sub][r] = val;
        vmax = fmaxf(vmax, val);
      }
    vmax = fmaxf(vmax, __shfl_xor(vmax, 16));
    vmax = fmaxf(vmax, __shfl_xor(vmax, 32));
    float m_new = fmaxf(m_i, vmax);
    float alpha = __builtin_amdgcn_exp2f(m_i - m_new);
    float rsum = 0.0f;
    f16x4 pF[4];
#pragma unroll
    for (int sub = 0; sub < 4; sub++) {
      f16x4 ph;
#pragma unroll
      for (int r = 0; r < 4; r++) {
        float e = __builtin_amdgcn_exp2f(st[sub][r] - m_new);
        rsum += e;
        ph[r] = (f16)e;
      }
      pF[sub] = ph;
    }
    rsum += __shfl_xor(rsum, 16);
    rsum += __shfl_xor(rsum, 32);
    l_i = l_i * alpha + rsum;
    m_i = m_new;
#pragma unroll
    for (int dt = 0; dt < 4; dt++)
#pragma unroll
      for (int r = 0; r < 4; r++) ot[dt][r] *= alpha;
    // O^T += V^T · P^T (P^T direct from St's C/D registers)
#pragma unroll
    for (int sub = 0; sub < 4; sub++)
#pragma unroll
      for (int dt = 0; dt < 4; dt++) {
        f16x4 vF = *(const f16x4*)(lV + (dt * 16 + q) * LDVT + sub * 16 + quad * 4);
        ot[dt] = __builtin_amdgcn_mfma_f32_16x16x16f16(vF, pF[sub], ot[dt], 0, 0, 0);
      }
  }

  // epilogue: normalize, transpose via LDS (reuse lK), coalesced f16 store
  const float inv = 1.0f / l_i;
  __syncthreads();  // all waves done with lK/lV MFMA reads
  f16* OT = lK + w * (16 * LDKK);  // 16 rows x 64 cols, stride LDKK
#pragma unroll
  for (int dt = 0; dt < 4; dt++) {
    f16x4 o4;
#pragma unroll
    for (int r = 0; r < 4; r++) o4[r] = (f16)(ot[dt][r] * inv);
    *(f16x4*)(OT + q * LDKK + dt * 16 + quad * 4) = o4;
  }
  __syncthreads();
  int row = lane >> 2, cs = lane & 3;
  f16x8 o8a = *(const f16x8*)(OT + row * LDKK + cs * 16);
  f16x8 o8b = *(const f16x8*)(OT + row * LDKK + cs * 16 + 8);
  f16* dst = att + (b * 2048 + q0 + w * 16 + row) * 1024 + h * 64 + cs * 16;
  *(f16x8*)dst = o8a;
  *(f16x8*)(dst + 8) = o8b;
}

// ---------------------------------------------------------- output projection
// A side: att (native f16 in ws). W side + output dtype: runtime-detected.
__global__ __launch_bounds__(256) void out_proj(
    const f16* __restrict__ att, const void* __restrict__ wo,
    void* __restrict__ out) {
  __shared__ __align__(16) f16 lA[128 * LDK];
  __shared__ __align__(16) f16 lW[128 * LDK];
  const int m0 = blockIdx.x * 128, n0 = blockIdx.y * 128;
  f32x4 acc[4][4];
  const f32x4 zero = {0.f, 0.f, 0.f, 0.f};
#pragma unroll
  for (int i = 0; i < 4; i++)
#pragma unroll
    for (int j = 0; j < 4; j++) acc[i][j] = zero;

  const bool bf = detect_bf16((const u16*)wo);
  if (bf)
    gemm_core<0, 1>(att, wo, m0, n0, lA, lW, acc);
  else
    gemm_core<0, 2>(att, wo, m0, n0, lA, lW, acc);

  const int tid = threadIdx.x, lane = tid & 63, w = tid >> 6;
  const int wm = w & 1, wn = w >> 1, q = lane & 15, quad = lane >> 4;
#pragma unroll
  for (int mt = 0; mt < 4; mt++)
#pragma unroll
    for (int nt = 0; nt < 4; nt++) {
      int n = n0 + wn * 64 + nt * 16 + q;
#pragma unroll
      for (int r = 0; r < 4; r++) {
        int mm = m0 + wm * 64 + mt * 16 + quad * 4 + r;
        if (bf)
          ((u16*)out)[mm * 1024 + n] = f2bf(acc[mt][nt][r]);
        else
          ((float*)out)[mm * 1024 + n] = acc[mt][nt][r];
      }
    }
}

// ------------------------------------------------------------------- launch
extern "C" void kernel_launch(void* const* d_in, const int* in_sizes, int n_in,
                              void* d_out, int out_size, void* d_ws, size_t ws_size,
                              hipStream_t stream) {
  const void* x  = d_in[0];
  const void* Wq = d_in[1];
  const void* Wk = d_in[2];
  const void* Wv = d_in[3];
  const void* Wo = d_in[4];
  char* ws = (char*)d_ws;
  const size_t MB = 1024 * 1024;
  f16* qb  = (f16*)(ws);            // (B,H,T,D) f16, 8 MB each
  f16* kb  = (f16*)(ws + 8 * MB);
  f16* vb  = (f16*)(ws + 16 * MB);
  f16* att = (f16*)(ws + 24 * MB);  // (B,T,C) f16, 8 MB -> total 32 MB

  qkv_proj<<<dim3(32, 8, 3), 256, 0, stream>>>(x, Wq, Wk, Wv, qb, kb, vb,
                                               0.125f * LOG2E);
  attn<<<dim3(32, 32), 256, 0, stream>>>(qb, kb, vb, att);
  out_proj<<<dim3(32, 8), 256, 0, stream>>>(att, Wo, d_out);
}